// Round 11
// baseline (115.634 us; speedup 1.0000x reference)
//
#include <hip/hip_runtime.h>
#include <hip/hip_bf16.h>
#include <hip/hip_fp16.h>

#define DD  256
#define HWD 1024
#define NN  32768
#define KK  1024
#define ZQ_SIZE (NN*DD)
#define IDX_OFF ZQ_SIZE
#define LOSS_OFF (ZQ_SIZE + NN)

// scratch layout (bytes) inside the z_q region of d_out (overwritten by gather)
#define CBH_OFF    0                      // fp16 codebook, 512 KB
#define CNORM_OFF  (KK*DD*2)              // 4 KB
#define ZSQ_OFF    (CNORM_OFF + KK*4)     // 256 floats (per-block zsq partials)
#define ROWREC_OFF (ZSQ_OFF + 4096)       // [row][16 chains] float4 = 8 MB

#define TH_REFINE 0.2f
#define LOSS_SCALE (0.25f / (float)ZQ_SIZE)

typedef __attribute__((ext_vector_type(8))) _Float16 h16x8;
typedef __attribute__((ext_vector_type(4))) float f32x4;

__device__ __forceinline__ short f16bits(float x) {
    _Float16 h = (_Float16)x;
    return *reinterpret_cast<short*>(&h);
}

// ---------------------------------------------------------------------------
// A: codebook -> fp16 + exact fp32 row norms
__global__ __launch_bounds__(256)
void vq_prep_kernel(const float* __restrict__ cb, unsigned char* __restrict__ scratch) {
    _Float16* cbh = (_Float16*)(scratch + CBH_OFF);
    float* cn = (float*)(scratch + CNORM_OFF);
    int t = threadIdx.x;
    int row = blockIdx.x * 16 + (t >> 4);   // grid 64
    int dq  = t & 15;
    const float* rp = cb + (size_t)row * DD + dq * 16;
    float nrm = 0.f;
    __attribute__((aligned(16))) _Float16 h[16];
#pragma unroll
    for (int i = 0; i < 4; ++i) {
        float4 v = *(const float4*)(rp + i * 4);
        float xs[4] = {v.x, v.y, v.z, v.w};
#pragma unroll
        for (int j = 0; j < 4; ++j) {
            float x = xs[j];
            h[i * 4 + j] = (_Float16)x;
            nrm = fmaf(x, x, nrm);
        }
    }
    *(uint4*)&cbh[(size_t)row * DD + dq * 16]     = *(uint4*)&h[0];
    *(uint4*)&cbh[(size_t)row * DD + dq * 16 + 8] = *(uint4*)&h[8];
#pragma unroll
    for (int m = 1; m < 16; m <<= 1) nrm += __shfl_xor(nrm, m, 64);
    if (dq == 0) cn[row] = nrm;
}

// ---------------------------------------------------------------------------
// B: register-streamed fp16 MFMA argmin. Grid 256 x 256 thr (1 block/CU,
// 1 wave/SIMD, full register file via waves_per_eu(1,1)). Each wave: 32 rows
// (A-frags in regs via coalesced z->LDS transpose prologue), sweeps all 1024
// codes in 64 tiles of 16; B-frags stream L2->VGPR double-buffered. NO
// barriers / NO LDS after the prologue. Each lane keeps per-chain top-2
// (chain = codes == ln15 mod 16) and dumps 8 float4 records to rowrec.
__global__ __launch_bounds__(256) __attribute__((amdgpu_waves_per_eu(1, 1)))
void vq_mfma_argmin_kernel(const float* __restrict__ z, unsigned char* __restrict__ scratch) {
    const unsigned char* cbh_b = scratch + CBH_OFF;
    const float* cn_g = (const float*)(scratch + CNORM_OFF);
    float* zsqp = (float*)(scratch + ZSQ_OFF);
    float* rowrec = (float*)(scratch + ROWREC_OFF);

    __shared__ short zl[128 * 256];          // 64 KB z tile (dead after prologue)
    __shared__ float zred[4];

    const int t    = threadIdx.x;
    const int w    = t >> 6;
    const int lane = t & 63;
    const int ln15 = lane & 15;
    const int lh   = lane >> 4;

    const int n0  = blockIdx.x * 128;        // 128 rows/block (4 waves x 32)
    const int b   = n0 >> 10;
    const int hw0 = n0 & 1023;

    // ---- phase 1: coalesced z -> LDS (fp16, transposed, swizzled) + zsq
    {
        const int td = t >> 5;               // 0..7   d sub-lane
        const int th = t & 31;               // rows th*4..th*4+3
        const float* zb = z + (size_t)b * DD * HWD + hw0 + th * 4;
        float zsq = 0.f;
#pragma unroll
        for (int p = 0; p < 32; ++p) {
            int d = p * 8 + td;
            float4 v = *(const float4*)(zb + (size_t)d * HWD);
            zsq = fmaf(v.x, v.x, zsq); zsq = fmaf(v.y, v.y, zsq);
            zsq = fmaf(v.z, v.z, zsq); zsq = fmaf(v.w, v.w, zsq);
            float xs[4] = {v.x, v.y, v.z, v.w};
#pragma unroll
            for (int i = 0; i < 4; ++i) {
                int row = th * 4 + i;
                zl[row * 256 + (d ^ ((row & 15) << 3))] = f16bits(xs[i]);
            }
        }
#pragma unroll
        for (int m = 1; m < 64; m <<= 1) zsq += __shfl_xor(zsq, m, 64);
        if (lane == 0) zred[w] = zsq;
    }
    __syncthreads();                          // only barrier in the kernel

    // ---- phase 2: A-frags to registers
    h16x8 ah[2][8];
#pragma unroll
    for (int nf = 0; nf < 2; ++nf)
#pragma unroll
        for (int ds = 0; ds < 8; ++ds) {
            int row = w * 32 + nf * 16 + ln15;
            int d0  = ds * 32 + lh * 8;
            ah[nf][ds] = *(const h16x8*)&zl[row * 256 + (d0 ^ ((row & 15) << 3))];
        }
    if (t == 0) zsqp[blockIdx.x] = (zred[0] + zred[1]) + (zred[2] + zred[3]);

    // ---- main loop: 64 tiles of 16 codes, B streamed L2 -> regs, dbuf'd
    const unsigned char* bp = cbh_b + (size_t)ln15 * 512 + lh * 16;
    const float* cnp = cn_g + ln15;

    float v1[8], k1f[8], v2[8], k2f[8];
#pragma unroll
    for (int s = 0; s < 8; ++s) { v1[s] = 3e38f; v2[s] = 3e38f; k1f[s] = 0.f; k2f[s] = 0.f; }

    h16x8 bA[8], bB[8];
    float cnA, cnB;

    auto COMPUTE = [&](const h16x8 (&bb)[8], float cnv, int tt) {
        f32x4 a0 = {0.f,0.f,0.f,0.f}, a1 = a0, a2 = a0, a3 = a0;
#pragma unroll
        for (int ds = 0; ds < 8; ds += 4) {
            a0 = __builtin_amdgcn_mfma_f32_16x16x32_f16(ah[0][ds + 0], bb[ds + 0], a0, 0, 0, 0);
            a1 = __builtin_amdgcn_mfma_f32_16x16x32_f16(ah[1][ds + 0], bb[ds + 0], a1, 0, 0, 0);
            a2 = __builtin_amdgcn_mfma_f32_16x16x32_f16(ah[0][ds + 1], bb[ds + 1], a2, 0, 0, 0);
            a3 = __builtin_amdgcn_mfma_f32_16x16x32_f16(ah[1][ds + 1], bb[ds + 1], a3, 0, 0, 0);
            a0 = __builtin_amdgcn_mfma_f32_16x16x32_f16(ah[0][ds + 2], bb[ds + 2], a0, 0, 0, 0);
            a1 = __builtin_amdgcn_mfma_f32_16x16x32_f16(ah[1][ds + 2], bb[ds + 2], a1, 0, 0, 0);
            a2 = __builtin_amdgcn_mfma_f32_16x16x32_f16(ah[0][ds + 3], bb[ds + 3], a2, 0, 0, 0);
            a3 = __builtin_amdgcn_mfma_f32_16x16x32_f16(ah[1][ds + 3], bb[ds + 3], a3, 0, 0, 0);
        }
        f32x4 s0 = a0 + a2, s1 = a1 + a3;    // nf=0, nf=1
        const float kgf = (float)(tt * 16 + ln15);
#pragma unroll
        for (int s = 0; s < 8; ++s) {
            float a = (s < 4) ? s0[s] : s1[s - 4];
            float dist = fmaf(-2.f, a, cnv);
            bool b1 = dist < v1[s];
            bool b2 = dist < v2[s];
            v2[s]  = b1 ? v1[s]  : (b2 ? dist : v2[s]);
            k2f[s] = b1 ? k1f[s] : (b2 ? kgf  : k2f[s]);
            v1[s]  = b1 ? dist : v1[s];
            k1f[s] = b1 ? kgf  : k1f[s];
        }
    };

    // prologue loads
    {
        const unsigned char* p0 = bp;
        const unsigned char* p1 = bp + 8192;
#pragma unroll
        for (int ds = 0; ds < 8; ++ds) {
            bA[ds] = *(const h16x8*)(p0 + ds * 64);
            bB[ds] = *(const h16x8*)(p1 + ds * 64);
        }
        cnA = cnp[0]; cnB = cnp[16];
    }

    for (int tt = 0; tt < 64; tt += 2) {
        COMPUTE(bA, cnA, tt);
        if (tt + 2 < 64) {
            const unsigned char* p = bp + (size_t)(tt + 2) * 8192;
#pragma unroll
            for (int ds = 0; ds < 8; ++ds) bA[ds] = *(const h16x8*)(p + ds * 64);
            cnA = cnp[(tt + 2) * 16];
        }
        COMPUTE(bB, cnB, tt + 1);
        if (tt + 3 < 64) {
            const unsigned char* p = bp + (size_t)(tt + 3) * 8192;
#pragma unroll
            for (int ds = 0; ds < 8; ++ds) bB[ds] = *(const h16x8*)(p + ds * 64);
            cnB = cnp[(tt + 3) * 16];
        }
    }

    // ---- epilogue: every lane dumps its 8 per-chain top-2 records
#pragma unroll
    for (int s = 0; s < 8; ++s) {
        int nf = s >> 2, r = s & 3;
        int row = w * 32 + nf * 16 + lh * 4 + r;   // C layout: row = lh*4+reg
        float4 e; e.x = v1[s]; e.y = k1f[s]; e.z = v2[s]; e.w = k2f[s];
        *(float4*)&rowrec[((size_t)(n0 + row) * 16 + ln15) * 4] = e;
    }
}

// ---------------------------------------------------------------------------
// R: per row scan 16 chains x top-2 -> top-6 (index tie-break); flag rows
// with gap <= TH; wave-coop exact fp32 recheck of the 6 candidates.
// Loss = sum chosen dist (+ zsq partials folded by block 0).
__global__ __launch_bounds__(256)
void vq_refine_kernel(const float* __restrict__ z, const float* __restrict__ cb,
                      const unsigned char* __restrict__ scratch, float* __restrict__ idx_out,
                      float* __restrict__ lossp) {
    const float* rowrec = (const float*)(scratch + ROWREC_OFF);
    const float* cn_g = (const float*)(scratch + CNORM_OFF);
    const float* zsqp = (const float*)(scratch + ZSQ_OFF);
    int n = blockIdx.x * 256 + threadIdx.x;   // grid 128
    int lane = threadIdx.x & 63;

    float uv[6], uk[6];
#pragma unroll
    for (int j = 0; j < 6; ++j) { uv[j] = 3e38f; uk[j] = 0.f; }
    auto INS = [&](float v, float k) {
#pragma unroll
        for (int j = 0; j < 6; ++j) {
            bool lt = (v < uv[j]) || (v == uv[j] && k < uk[j]);
            float tv = uv[j], tk = uk[j];
            uv[j] = lt ? v : tv; uk[j] = lt ? k : tk;
            v = lt ? tv : v;     k = lt ? tk : k;
        }
    };
    {
        const float4* rr = (const float4*)(rowrec + (size_t)n * 64);
#pragma unroll
        for (int c = 0; c < 16; ++c) {
            float4 e = rr[c];
            INS(e.x, e.y);
            INS(e.z, e.w);
        }
    }

    bool flag = (uv[1] - uv[0]) <= TH_REFINE;
    float lp = 0.f;
    if (!flag) { idx_out[n] = uk[0]; lp = uv[0]; }

    unsigned long long mask = __ballot(flag);
    while (mask) {
        int li = __ffsll(mask) - 1;
        mask &= mask - 1;
        int nn = __shfl(n, li);
        int kc[6];
#pragma unroll
        for (int j = 0; j < 6; ++j) kc[j] = (int)__shfl(uk[j], li);
        int bb = nn >> 10, hw = nn & 1023;
        const float* zp = z + (size_t)bb * DD * HWD + hw;
        float s[6] = {0.f, 0.f, 0.f, 0.f, 0.f, 0.f};
#pragma unroll
        for (int j = 0; j < 4; ++j) {
            int d = lane + 64 * j;
            float zv = zp[(size_t)d * HWD];
#pragma unroll
            for (int q = 0; q < 6; ++q)
                s[q] = fmaf(zv, cb[(size_t)kc[q] * DD + d], s[q]);
        }
#pragma unroll
        for (int m = 32; m >= 1; m >>= 1)
#pragma unroll
            for (int q = 0; q < 6; ++q) s[q] += __shfl_xor(s[q], m, 64);
        float dch = 3e38f; int kch = 0;
#pragma unroll
        for (int q = 0; q < 6; ++q) {
            float dq = cn_g[kc[q]] - 2.f * s[q];
            if (dq < dch || (dq == dch && kc[q] < kch)) { dch = dq; kch = kc[q]; }
        }
        if (lane == 0) { idx_out[nn] = (float)kch; lp += dch; }
    }

    // fold zsq partials (block 0; 256 floats, 1/thread)
    if (blockIdx.x == 0) lp += zsqp[threadIdx.x];

#pragma unroll
    for (int m = 32; m >= 1; m >>= 1) lp += __shfl_xor(lp, m, 64);
    __shared__ float bl[4];
    if (lane == 0) bl[threadIdx.x >> 6] = lp;
    __syncthreads();
    if (threadIdx.x == 0)
        atomicAdd(lossp, (bl[0] + bl[1] + bl[2] + bl[3]) * LOSS_SCALE);
}

// ---------------------------------------------------------------------------
// C: pure gather z_q = codebook[idx] (tiled via LDS, coalesced writes)
__global__ __launch_bounds__(256)
void vq_gather_kernel(const float* __restrict__ cb, float* __restrict__ out) {
    const float* idxf = out + IDX_OFF;
    __shared__ float crow[64][257];
    __shared__ int kidx[64];
    int t = threadIdx.x;
    int w = t >> 6, lane = t & 63;
    int n0 = blockIdx.x * 64;                      // grid 512
    int b = n0 >> 10, hw0 = n0 & 1023;
    if (t < 64) kidx[t] = (int)idxf[n0 + t];
    __syncthreads();
    for (int i = 0; i < 16; ++i) {
        int r = w * 16 + i;
        int k = kidx[r];
        float4 v = *(const float4*)(cb + (size_t)k * DD + lane * 4);
        crow[r][lane * 4 + 0] = v.x; crow[r][lane * 4 + 1] = v.y;
        crow[r][lane * 4 + 2] = v.z; crow[r][lane * 4 + 3] = v.w;
    }
    __syncthreads();
    const int zph = t >> 6, hwl = t & 63;
#pragma unroll 4
    for (int dd = 0; dd < 64; ++dd) {
        int d = dd * 4 + zph;
        size_t o = (size_t)b * (DD * HWD) + (size_t)d * HWD + hw0 + hwl;
        out[o] = crow[hwl][d];
    }
}

// ---------------------------------------------------------------------------
extern "C" void kernel_launch(void* const* d_in, const int* in_sizes, int n_in,
                              void* d_out, int out_size, void* d_ws, size_t ws_size,
                              hipStream_t stream) {
    const float* z  = (const float*)d_in[0];
    const float* cb = (const float*)d_in[1];
    float* out = (float*)d_out;
    unsigned char* scratch = (unsigned char*)d_out;   // z_q region, overwritten by gather

    hipMemsetAsync((void*)(out + LOSS_OFF), 0, sizeof(float), stream);

    vq_prep_kernel<<<64, 256, 0, stream>>>(cb, scratch);
    vq_mfma_argmin_kernel<<<256, 256, 0, stream>>>(z, scratch);
    vq_refine_kernel<<<128, 256, 0, stream>>>(z, cb, scratch, out + IDX_OFF, out + LOSS_OFF);
    vq_gather_kernel<<<512, 256, 0, stream>>>(cb, out);
}

// Round 12
// 82.805 us; speedup vs baseline: 1.3965x; 1.3965x over previous
//
#include <hip/hip_runtime.h>
#include <hip/hip_bf16.h>
#include <hip/hip_fp16.h>

#define DD  256
#define HWD 1024
#define NN  32768
#define KK  1024
#define ZQ_SIZE (NN*DD)
#define IDX_OFF ZQ_SIZE
#define LOSS_OFF (ZQ_SIZE + NN)

// scratch layout (bytes) inside the z_q region of d_out (overwritten by gather)
#define CBH_OFF    0                      // fp16 codebook, 512 KB
#define CNORM_OFF  (KK*DD*2)              // 4 KB
#define ZSQ_OFF    (CNORM_OFF + KK*4)     // 512 floats (per-row-tile zsq partials)
#define ROWREC_OFF (ZSQ_OFF + 4096)       // [khalf][row] * 8 floats = 2 MB

#define TH_REFINE 0.2f
#define LOSS_SCALE (0.25f / (float)ZQ_SIZE)

typedef __attribute__((ext_vector_type(8))) _Float16 h16x8;
typedef __attribute__((ext_vector_type(4))) float f32x4;

__device__ __forceinline__ void gload16(const void* g, void* l) {
    __builtin_amdgcn_global_load_lds(
        (const __attribute__((address_space(1))) void*)g,
        (__attribute__((address_space(3))) void*)l, 16, 0, 0);
}
__device__ __forceinline__ short f16bits(float x) {
    _Float16 h = (_Float16)x;
    return *reinterpret_cast<short*>(&h);
}
__device__ __forceinline__ void ins3(float v, float k, float& u1, float& e1,
                                     float& u2, float& e2, float& u3, float& e3) {
    bool l1 = v < u1, l2 = v < u2, l3 = v < u3;
    u3 = l2 ? u2 : (l3 ? v : u3);  e3 = l2 ? e2 : (l3 ? k : e3);
    u2 = l1 ? u1 : (l2 ? v : u2);  e2 = l1 ? e1 : (l2 ? k : e2);
    u1 = l1 ? v : u1;              e1 = l1 ? k : e1;
}

// ---------------------------------------------------------------------------
// A: codebook -> fp16 + exact fp32 row norms
__global__ __launch_bounds__(256)
void vq_prep_kernel(const float* __restrict__ cb, unsigned char* __restrict__ scratch) {
    _Float16* cbh = (_Float16*)(scratch + CBH_OFF);
    float* cn = (float*)(scratch + CNORM_OFF);
    int t = threadIdx.x;
    int row = blockIdx.x * 16 + (t >> 4);   // grid 64
    int dq  = t & 15;
    const float* rp = cb + (size_t)row * DD + dq * 16;
    float nrm = 0.f;
    __attribute__((aligned(16))) _Float16 h[16];
#pragma unroll
    for (int i = 0; i < 4; ++i) {
        float4 v = *(const float4*)(rp + i * 4);
        float xs[4] = {v.x, v.y, v.z, v.w};
#pragma unroll
        for (int j = 0; j < 4; ++j) {
            float x = xs[j];
            h[i * 4 + j] = (_Float16)x;
            nrm = fmaf(x, x, nrm);
        }
    }
    *(uint4*)&cbh[(size_t)row * DD + dq * 16]     = *(uint4*)&h[0];
    *(uint4*)&cbh[(size_t)row * DD + dq * 16 + 8] = *(uint4*)&h[8];
#pragma unroll
    for (int m = 1; m < 16; m <<= 1) nrm += __shfl_xor(nrm, m, 64);
    if (dq == 0) cn[row] = nrm;
}

// ---------------------------------------------------------------------------
// B: fp16 MFMA distance-argmin. Grid 1024 = 512 row-tiles x 2 k-halves.
// 256 thr = 4 waves (2 row-groups x 2 k-quarters), 64 rows/blk, 512 codes/blk
// in 16 tiles of 32, 3-deep staging buffers, vmcnt(4) counted waits (never 0
// mid-loop). LDS ~51 KB -> 3 blocks/CU (12 waves = 3/SIMD).
__global__ __launch_bounds__(256) __attribute__((amdgpu_waves_per_eu(3, 3)))
void vq_mfma_argmin_kernel(const float* __restrict__ z, unsigned char* __restrict__ scratch) {
    const unsigned char* cbh_b = scratch + CBH_OFF;
    const float* cn_g = (const float*)(scratch + CNORM_OFF);
    float* zsqp = (float*)(scratch + ZSQ_OFF);
    float* rowrec = (float*)(scratch + ROWREC_OFF);

    __shared__ __attribute__((aligned(16))) short bufs[3 * 8192];  // 48 KB (z tile aliases [0..2))
    __shared__ float cn_l[512];                                    // 2 KB
    __shared__ float zred[4];
    __shared__ float2 ep[2][64][3];                                // 3 KB cross-wave merge

    const int t    = threadIdx.x;
    const int w    = t >> 6;
    const int lane = t & 63;
    const int ln15 = lane & 15;
    const int lh   = lane >> 4;
    const int g    = w >> 1;         // row-group 0..1 (32 rows each)
    const int kq   = w & 1;          // 16-code quarter of each 32-code tile

    const int bid = blockIdx.x;
    const int kh  = bid & 1;         // k-half: codes kh*512 .. +511
    const int rt  = bid >> 1;        // row-tile
    const int n0  = rt * 64;
    const int b   = n0 >> 10;
    const int hw0 = n0 & 1023;

    const int ksub  = lane >> 5;
    const int chunk = lane & 31;

    const int klr   = kq * 16 + ln15;        // code row within 32-code tile
    const int rbase = klr * 256;             // shorts
    const int rxor  = (klr & 7) << 3;

    // cn -> LDS (visible after prologue barrier)
    {
        float2 c = *(const float2*)(cn_g + kh * 512 + t * 2);
        *(float2*)&cn_l[t * 2] = c;
    }

    // ---- phase 1: coalesced z -> LDS (fp16, transposed, swizzled) + zsq
    {
        short* zlds = bufs;
        const int zd = t >> 4;               // 0..15
        const int zq = t & 15;
        const float* zb = z + (size_t)b * DD * HWD + hw0 + zq * 4;
        float zsq = 0.f;
#pragma unroll
        for (int p = 0; p < 16; ++p) {
            int d = p * 16 + zd;
            float4 v = *(const float4*)(zb + (size_t)d * HWD);
            zsq = fmaf(v.x, v.x, zsq); zsq = fmaf(v.y, v.y, zsq);
            zsq = fmaf(v.z, v.z, zsq); zsq = fmaf(v.w, v.w, zsq);
            float xs[4] = {v.x, v.y, v.z, v.w};
#pragma unroll
            for (int i = 0; i < 4; ++i) {
                int row = zq * 4 + i;
                zlds[row * 256 + (d ^ ((row & 15) << 3))] = f16bits(xs[i]);
            }
        }
#pragma unroll
        for (int m = 1; m < 64; m <<= 1) zsq += __shfl_xor(zsq, m, 64);
        if (lane == 0) zred[w] = zsq;
    }
    __syncthreads();

    // ---- phase 2: A-frags from LDS
    h16x8 ah[2][8];
#pragma unroll
    for (int nf = 0; nf < 2; ++nf)
#pragma unroll
        for (int ds = 0; ds < 8; ++ds) {
            int row = g * 32 + nf * 16 + ln15;
            int d0  = ds * 32 + lh * 8;
            ah[nf][ds] = *(const h16x8*)&bufs[row * 256 + (d0 ^ ((row & 15) << 3))];
        }
    if (kh == 0 && t == 0) zsqp[rt] = (zred[0] + zred[1]) + (zred[2] + zred[3]);
    __syncthreads();   // frag reads done before staging overwrites bufs

    // stage tile tt (32 codes, 16 KB) into bufs[tt%3]: 16 slices, 4 per wave
    auto STAGE = [&](int tt) {
        short* dstb = &bufs[(tt % 3) * 8192];
#pragma unroll
        for (int si = 0; si < 4; ++si) {
            int s  = w * 4 + si;
            int kl = s * 2 + ksub;
            const unsigned char* src = cbh_b
                + (size_t)(kh * 512 + tt * 32 + kl) * 512 + ((chunk ^ (kl & 7)) << 4);
            gload16(src, &dstb[s * 512]);
        }
    };

    float v1[8], k1f[8], v2[8], k2f[8];
#pragma unroll
    for (int s = 0; s < 8; ++s) { v1[s] = 3e38f; v2[s] = 3e38f; k1f[s] = 0.f; k2f[s] = 0.f; }

    auto COMPUTE = [&](int kt) {
        const short* cbt = &bufs[(kt % 3) * 8192];
        const float cnv = cn_l[kt * 32 + klr];
        const float kgf = (float)(kh * 512 + kt * 32 + klr);
        f32x4 c0 = {0.f,0.f,0.f,0.f}, c1 = c0, c2 = c0, c3 = c0;
#pragma unroll
        for (int ds = 0; ds < 8; ds += 2) {
            const int ib0 = rbase + (((ds + 0) * 32 + lh * 8) ^ rxor);
            const int ib1 = rbase + (((ds + 1) * 32 + lh * 8) ^ rxor);
            h16x8 b0 = *(const h16x8*)&cbt[ib0];
            h16x8 b1 = *(const h16x8*)&cbt[ib1];
            c0 = __builtin_amdgcn_mfma_f32_16x16x32_f16(ah[0][ds + 0], b0, c0, 0, 0, 0);
            c2 = __builtin_amdgcn_mfma_f32_16x16x32_f16(ah[1][ds + 0], b0, c2, 0, 0, 0);
            c1 = __builtin_amdgcn_mfma_f32_16x16x32_f16(ah[0][ds + 1], b1, c1, 0, 0, 0);
            c3 = __builtin_amdgcn_mfma_f32_16x16x32_f16(ah[1][ds + 1], b1, c3, 0, 0, 0);
        }
        f32x4 s0 = c0 + c1, s1 = c2 + c3;
#pragma unroll
        for (int s = 0; s < 8; ++s) {
            float a = (s < 4) ? s0[s] : s1[s - 4];
            float dist = fmaf(-2.f, a, cnv);
            bool b1c = dist < v1[s];
            bool b2c = dist < v2[s];
            v2[s]  = b1c ? v1[s]  : (b2c ? dist : v2[s]);
            k2f[s] = b1c ? k1f[s] : (b2c ? kgf  : k2f[s]);
            v1[s]  = b1c ? dist : v1[s];
            k1f[s] = b1c ? kgf  : k1f[s];
        }
    };

    // prologue: 2 tiles in flight
    STAGE(0); STAGE(1);

    for (int kt = 0; kt < 14; ++kt) {
        asm volatile("s_waitcnt vmcnt(4)" ::: "memory");   // tile kt landed
        __builtin_amdgcn_sched_barrier(0);
        __builtin_amdgcn_s_barrier();
        __builtin_amdgcn_sched_barrier(0);
        STAGE(kt + 2);                                     // into buf (kt+2)%3 = (kt-1)%3
        COMPUTE(kt);
    }
    asm volatile("s_waitcnt vmcnt(4)" ::: "memory");
    __builtin_amdgcn_sched_barrier(0);
    __builtin_amdgcn_s_barrier();
    __builtin_amdgcn_sched_barrier(0);
    COMPUTE(14);
    asm volatile("s_waitcnt vmcnt(0)" ::: "memory");
    __builtin_amdgcn_sched_barrier(0);
    __builtin_amdgcn_s_barrier();
    __builtin_amdgcn_sched_barrier(0);
    COMPUTE(15);

    // ---- epilogue: 16-lane shfl merge keeping top-3 (register-only)
    float u3[8], e3[8];
#pragma unroll
    for (int s = 0; s < 8; ++s) { u3[s] = 3e38f; e3[s] = 0.f; }
#pragma unroll
    for (int m = 1; m < 16; m <<= 1) {
#pragma unroll
        for (int s = 0; s < 8; ++s) {
            float o1 = __shfl_xor(v1[s],  m, 64);
            float p1 = __shfl_xor(k1f[s], m, 64);
            float o2 = __shfl_xor(v2[s],  m, 64);
            float p2 = __shfl_xor(k2f[s], m, 64);
            float o3 = __shfl_xor(u3[s],  m, 64);
            float p3 = __shfl_xor(e3[s],  m, 64);
            ins3(o1, p1, v1[s], k1f[s], v2[s], k2f[s], u3[s], e3[s]);
            ins3(o2, p2, v1[s], k1f[s], v2[s], k2f[s], u3[s], e3[s]);
            ins3(o3, p3, v1[s], k1f[s], v2[s], k2f[s], u3[s], e3[s]);
        }
    }
    __syncthreads();   // bufs reads all done; reuse ep region safely anyway
    if (ln15 == 0) {
#pragma unroll
        for (int s = 0; s < 8; ++s) {
            int nf = s >> 2, r = s & 3;
            int row = g * 32 + nf * 16 + lh * 4 + r;    // C layout: row = lh*4+reg
            ep[kq][row][0] = make_float2(v1[s], k1f[s]);
            ep[kq][row][1] = make_float2(v2[s], k2f[s]);
            ep[kq][row][2] = make_float2(u3[s], e3[s]);
        }
    }
    __syncthreads();
    if (t < 64) {                    // merge the 2 k-quarters -> per-row top-3
        float a1 = 3e38f, b1 = 0.f, a2 = 3e38f, b2 = 0.f, a3 = 3e38f, b3 = 0.f;
#pragma unroll
        for (int q = 0; q < 2; ++q)
#pragma unroll
            for (int e = 0; e < 3; ++e) {
                float2 x = ep[q][t][e];
                ins3(x.x, x.y, a1, b1, a2, b2, a3, b3);
            }
        size_t base = ((size_t)kh * NN + n0 + t) * 8;
        float4 ra; ra.x = a1; ra.y = b1; ra.z = a2; ra.w = b2;
        float4 rb; rb.x = a3; rb.y = b3; rb.z = 0.f; rb.w = 0.f;
        *(float4*)&rowrec[base]     = ra;
        *(float4*)&rowrec[base + 4] = rb;
    }
}

// ---------------------------------------------------------------------------
// R: merge 2 k-halves x top-3 -> top-3; flagged rows (gap <= TH) get exact
// fp32 recheck. Loss = sum chosen dist + zsq partials (block 0).
__global__ __launch_bounds__(256)
void vq_refine_kernel(const float* __restrict__ z, const float* __restrict__ cb,
                      const unsigned char* __restrict__ scratch, float* __restrict__ idx_out,
                      float* __restrict__ lossp) {
    const float* rowrec = (const float*)(scratch + ROWREC_OFF);
    const float* cn_g = (const float*)(scratch + CNORM_OFF);
    const float* zsqp = (const float*)(scratch + ZSQ_OFF);
    int n = blockIdx.x * 256 + threadIdx.x;   // grid 128
    int lane = threadIdx.x & 63;

    float u1 = 3e38f, u2 = 3e38f, u3 = 3e38f, e1 = 0.f, e2 = 0.f, e3 = 0.f;
#pragma unroll
    for (int h = 0; h < 2; ++h) {
        size_t base = ((size_t)h * NN + n) * 8;
        float4 ra = *(const float4*)&rowrec[base];
        float4 rb = *(const float4*)&rowrec[base + 4];
        ins3(ra.x, ra.y, u1, e1, u2, e2, u3, e3);
        ins3(ra.z, ra.w, u1, e1, u2, e2, u3, e3);
        ins3(rb.x, rb.y, u1, e1, u2, e2, u3, e3);
    }

    bool flag = (u2 - u1) <= TH_REFINE;
    float lp = 0.f;
    if (!flag) { idx_out[n] = e1; lp = u1; }

    unsigned long long mask = __ballot(flag);
    while (mask) {
        int li = __ffsll(mask) - 1;
        mask &= mask - 1;
        int nn  = __shfl(n, li);
        int kk1 = (int)__shfl(e1, li);
        int kk2 = (int)__shfl(e2, li);
        int kk3 = (int)__shfl(e3, li);
        int bb = nn >> 10, hw = nn & 1023;
        const float* zp  = z  + (size_t)bb * DD * HWD + hw;
        const float* c1p = cb + (size_t)kk1 * DD;
        const float* c2p = cb + (size_t)kk2 * DD;
        const float* c3p = cb + (size_t)kk3 * DD;
        float s1 = 0.f, s2 = 0.f, s3 = 0.f;
#pragma unroll
        for (int j = 0; j < 4; ++j) {
            int d = lane + 64 * j;
            float zv = zp[(size_t)d * HWD];
            s1 = fmaf(zv, c1p[d], s1);
            s2 = fmaf(zv, c2p[d], s2);
            s3 = fmaf(zv, c3p[d], s3);
        }
#pragma unroll
        for (int m = 32; m >= 1; m >>= 1) {
            s1 += __shfl_xor(s1, m, 64);
            s2 += __shfl_xor(s2, m, 64);
            s3 += __shfl_xor(s3, m, 64);
        }
        float d1 = cn_g[kk1] - 2.f * s1;
        float d2 = cn_g[kk2] - 2.f * s2;
        float d3 = cn_g[kk3] - 2.f * s3;
        float dch = d1; int kch = kk1;
        if (d2 < dch || (d2 == dch && kk2 < kch)) { dch = d2; kch = kk2; }
        if (d3 < dch || (d3 == dch && kk3 < kch)) { dch = d3; kch = kk3; }
        if (lane == 0) { idx_out[nn] = (float)kch; lp += dch; }
    }

    // fold zsq partials (block 0; 512 floats, 2/thread)
    if (blockIdx.x == 0) {
        const float2 zv = *(const float2*)&zsqp[threadIdx.x * 2];
        lp += zv.x + zv.y;
    }
#pragma unroll
    for (int m = 32; m >= 1; m >>= 1) lp += __shfl_xor(lp, m, 64);
    __shared__ float bl[4];
    if (lane == 0) bl[threadIdx.x >> 6] = lp;
    __syncthreads();
    if (threadIdx.x == 0)
        atomicAdd(lossp, (bl[0] + bl[1] + bl[2] + bl[3]) * LOSS_SCALE);
}

// ---------------------------------------------------------------------------
// C: pure gather z_q = codebook[idx] (tiled via LDS, coalesced writes)
__global__ __launch_bounds__(256)
void vq_gather_kernel(const float* __restrict__ cb, float* __restrict__ out) {
    const float* idxf = out + IDX_OFF;
    __shared__ float crow[64][257];
    __shared__ int kidx[64];
    int t = threadIdx.x;
    int w = t >> 6, lane = t & 63;
    int n0 = blockIdx.x * 64;                      // grid 512
    int b = n0 >> 10, hw0 = n0 & 1023;
    if (t < 64) kidx[t] = (int)idxf[n0 + t];
    __syncthreads();
    for (int i = 0; i < 16; ++i) {
        int r = w * 16 + i;
        int k = kidx[r];
        float4 v = *(const float4*)(cb + (size_t)k * DD + lane * 4);
        crow[r][lane * 4 + 0] = v.x; crow[r][lane * 4 + 1] = v.y;
        crow[r][lane * 4 + 2] = v.z; crow[r][lane * 4 + 3] = v.w;
    }
    __syncthreads();
    const int zph = t >> 6, hwl = t & 63;
#pragma unroll 4
    for (int dd = 0; dd < 64; ++dd) {
        int d = dd * 4 + zph;
        size_t o = (size_t)b * (DD * HWD) + (size_t)d * HWD + hw0 + hwl;
        out[o] = crow[hwl][d];
    }
}

// ---------------------------------------------------------------------------
extern "C" void kernel_launch(void* const* d_in, const int* in_sizes, int n_in,
                              void* d_out, int out_size, void* d_ws, size_t ws_size,
                              hipStream_t stream) {
    const float* z  = (const float*)d_in[0];
    const float* cb = (const float*)d_in[1];
    float* out = (float*)d_out;
    unsigned char* scratch = (unsigned char*)d_out;   // z_q region, overwritten by gather

    hipMemsetAsync((void*)(out + LOSS_OFF), 0, sizeof(float), stream);

    vq_prep_kernel<<<64, 256, 0, stream>>>(cb, scratch);
    vq_mfma_argmin_kernel<<<1024, 256, 0, stream>>>(z, scratch);
    vq_refine_kernel<<<128, 256, 0, stream>>>(z, cb, scratch, out + IDX_OFF, out + LOSS_OFF);
    vq_gather_kernel<<<512, 256, 0, stream>>>(cb, out);
}